// Round 1
// baseline (963.199 us; speedup 1.0000x reference)
//
#include <hip/hip_runtime.h>
#include <math.h>

constexpr int kB = 4;
constexpr int kC = 256;
constexpr int kL = 2048;
constexpr int kH = 8;
constexpr int kD = 32;      // head dim
constexpr int kG = 32;      // num groups
constexpr int kCPG = kC / kG; // 8 channels per group

// ---------------------------------------------------------------------------
// GroupNorm: one block per (b, group). Group = 8 channels x 2048 = 16384 floats,
// contiguous in memory.
// ---------------------------------------------------------------------------
__global__ __launch_bounds__(256) void gn_kernel(const float* __restrict__ x,
                                                 const float* __restrict__ w,
                                                 const float* __restrict__ bb,
                                                 float* __restrict__ h) {
    int grp = blockIdx.x;           // b*kG + g
    int b = grp / kG, g = grp % kG;
    const float* xp = x + ((size_t)b * kC + (size_t)g * kCPG) * kL;
    float* hp = h + ((size_t)b * kC + (size_t)g * kCPG) * kL;
    int t = threadIdx.x;
    const float4* x4 = (const float4*)xp;

    float s = 0.f, ss = 0.f;
#pragma unroll
    for (int i = 0; i < 16; ++i) {
        float4 v = x4[t + i * 256];
        s  += v.x + v.y + v.z + v.w;
        ss += v.x * v.x + v.y * v.y + v.z * v.z + v.w * v.w;
    }
    // wave reduce (64 lanes)
#pragma unroll
    for (int off = 32; off; off >>= 1) {
        s  += __shfl_down(s, off);
        ss += __shfl_down(ss, off);
    }
    __shared__ float red[8];
    int wave = t >> 6;
    if ((t & 63) == 0) { red[wave] = s; red[4 + wave] = ss; }
    __syncthreads();
    s  = red[0] + red[1] + red[2] + red[3];
    ss = red[4] + red[5] + red[6] + red[7];
    float mean = s * (1.f / 16384.f);
    float var  = ss * (1.f / 16384.f) - mean * mean;
    float rstd = rsqrtf(var + 1e-5f);

    float4* h4 = (float4*)hp;
#pragma unroll
    for (int i = 0; i < 16; ++i) {
        int idx = t + i * 256;                 // float4 index within group
        int c = g * kCPG + ((idx * 4) >> 11);  // channel (L=2048 per channel)
        float wc = w[c] * rstd;
        float bc = bb[c];
        float4 v = x4[idx];
        v.x = (v.x - mean) * wc + bc;
        v.y = (v.y - mean) * wc + bc;
        v.z = (v.z - mean) * wc + bc;
        v.w = (v.w - mean) * wc + bc;
        h4[idx] = v;
    }
}

// ---------------------------------------------------------------------------
// fp32 tiled GEMM: out[b,m,n] = sum_k W[m,k] * X[b,k,n] + bias[m] (+ resid)
// K fixed = 256, N fixed = kL. Tile 64x64, BK=16, 256 threads, 4x4 micro-tile.
// ---------------------------------------------------------------------------
template <bool RESIDUAL>
__global__ __launch_bounds__(256) void gemm_kernel(
    const float* __restrict__ W,      // [M,256]
    const float* __restrict__ X,      // [B][256][kL]
    const float* __restrict__ bias,   // [M]
    const float* __restrict__ resid,  // [B][M][kL] or nullptr
    float* __restrict__ out,          // [B][M][kL]
    int M) {
    constexpr int BK = 16;
    __shared__ alignas(16) float As[BK][64];  // [k][m]
    __shared__ alignas(16) float Bs[BK][64];  // [k][n]

    int t = threadIdx.x;
    int n0 = blockIdx.x * 64;
    int m0 = blockIdx.y * 64;
    int b  = blockIdx.z;
    const float* Xb = X + (size_t)b * 256 * kL;

    int tx = t & 15, ty = t >> 4;
    int am = t >> 2, ak = (t & 3) * 4;
    const float* Arow = W + (size_t)(m0 + am) * 256 + ak;

    float acc[4][4] = {};

    for (int k0 = 0; k0 < 256; k0 += BK) {
        __syncthreads();
        float4 a4 = *(const float4*)(Arow + k0);
        As[ak + 0][am] = a4.x;
        As[ak + 1][am] = a4.y;
        As[ak + 2][am] = a4.z;
        As[ak + 3][am] = a4.w;
        *(float4*)&Bs[ty][tx * 4] =
            *(const float4*)(Xb + (size_t)(k0 + ty) * kL + n0 + tx * 4);
        __syncthreads();
#pragma unroll
        for (int k = 0; k < BK; ++k) {
            float4 av = *(const float4*)&As[k][ty * 4];
            float4 bv = *(const float4*)&Bs[k][tx * 4];
            float a[4] = {av.x, av.y, av.z, av.w};
            float bvv[4] = {bv.x, bv.y, bv.z, bv.w};
#pragma unroll
            for (int i = 0; i < 4; ++i)
#pragma unroll
                for (int j = 0; j < 4; ++j) acc[i][j] += a[i] * bvv[j];
        }
    }

    int m = m0 + ty * 4, n = n0 + tx * 4;
#pragma unroll
    for (int i = 0; i < 4; ++i) {
        float bi = bias[m + i];
        float4 r;
        r.x = acc[i][0] + bi;
        r.y = acc[i][1] + bi;
        r.z = acc[i][2] + bi;
        r.w = acc[i][3] + bi;
        if (RESIDUAL) {
            float4 xr = *(const float4*)(resid + ((size_t)b * M + m + i) * kL + n);
            r.x += xr.x; r.y += xr.y; r.z += xr.z; r.w += xr.w;
        }
        *(float4*)(out + ((size_t)b * M + m + i) * kL + n) = r;
    }
}

// ---------------------------------------------------------------------------
// Flash attention, fp32 vector. One thread per query position.
// qkv layout: [B][768][kL]; q rows = h*32+d, k rows = 256+h*32+d, v = 512+...
// ---------------------------------------------------------------------------
__global__ __launch_bounds__(256) void attn_kernel(const float* __restrict__ qkv,
                                                   float* __restrict__ h2) {
    int t = threadIdx.x;
    int n = blockIdx.x * 256 + t;
    int hh = blockIdx.y, b = blockIdx.z;
    const size_t base = ((size_t)b * 768 + (size_t)hh * 32) * kL;
    const float* qp = qkv + base + n;
    const float* kp = qkv + base + (size_t)256 * kL;
    const float* vp = qkv + base + (size_t)512 * kL;
    constexpr float scale = 0.17677669529663687f;  // 1/sqrt(32)

    float q[32];
#pragma unroll
    for (int d = 0; d < 32; ++d) q[d] = qp[(size_t)d * kL] * scale;

    __shared__ alignas(16) float Ks[32][64];
    __shared__ alignas(16) float Vs[32][64];

    float mx = -3.0e38f, sum = 0.f;
    float acc[32];
#pragma unroll
    for (int d = 0; d < 32; ++d) acc[d] = 0.f;

    for (int m0 = 0; m0 < kL; m0 += 64) {
        __syncthreads();
#pragma unroll
        for (int i = 0; i < 2; ++i) {
            int idx = t + i * 256;      // 512 float4 per matrix
            int d = idx >> 4, c4 = idx & 15;
            *(float4*)&Ks[d][c4 * 4] = *(const float4*)(kp + (size_t)d * kL + m0 + c4 * 4);
            *(float4*)&Vs[d][c4 * 4] = *(const float4*)(vp + (size_t)d * kL + m0 + c4 * 4);
        }
        __syncthreads();
#pragma unroll 4
        for (int mm = 0; mm < 64; ++mm) {
            float s = 0.f;
#pragma unroll
            for (int d = 0; d < 32; ++d) s += q[d] * Ks[d][mm];
            if (s > mx) {
                float corr = __expf(mx - s);
                mx = s;
                sum = sum * corr + 1.f;
#pragma unroll
                for (int d = 0; d < 32; ++d) acc[d] = acc[d] * corr + Vs[d][mm];
            } else {
                float p = __expf(s - mx);
                sum += p;
#pragma unroll
                for (int d = 0; d < 32; ++d) acc[d] += p * Vs[d][mm];
            }
        }
    }
    float inv = 1.f / sum;
    float* op = h2 + ((size_t)b * 256 + (size_t)hh * 32) * kL + n;
#pragma unroll
    for (int d = 0; d < 32; ++d) op[(size_t)d * kL] = acc[d] * inv;
}

// ---------------------------------------------------------------------------
extern "C" void kernel_launch(void* const* d_in, const int* in_sizes, int n_in,
                              void* d_out, int out_size, void* d_ws, size_t ws_size,
                              hipStream_t stream) {
    const float* x     = (const float*)d_in[0];
    const float* gn_w  = (const float*)d_in[1];
    const float* gn_b  = (const float*)d_in[2];
    const float* qkv_w = (const float*)d_in[3];
    const float* qkv_b = (const float*)d_in[4];
    const float* out_w = (const float*)d_in[5];
    const float* out_b = (const float*)d_in[6];
    float* out = (float*)d_out;

    char* ws = (char*)d_ws;
    float* h   = (float*)ws;                                // 8 MiB
    float* qkv = (float*)(ws + (size_t)8 * 1024 * 1024);    // 24 MiB
    float* h2  = (float*)(ws + (size_t)32 * 1024 * 1024);   // 8 MiB

    gn_kernel<<<dim3(kB * kG), 256, 0, stream>>>(x, gn_w, gn_b, h);
    gemm_kernel<false><<<dim3(kL / 64, 768 / 64, kB), 256, 0, stream>>>(
        qkv_w, h, qkv_b, nullptr, qkv, 768);
    attn_kernel<<<dim3(kL / 256, kH, kB), 256, 0, stream>>>(qkv, h2);
    gemm_kernel<true><<<dim3(kL / 64, 256 / 64, kB), 256, 0, stream>>>(
        out_w, h2, out_b, x, out, 256);
}

// Round 2
// 133.776 us; speedup vs baseline: 7.2001x; 7.2001x over previous
//
#include <hip/hip_runtime.h>
#include <math.h>

using f32x4  = __attribute__((ext_vector_type(4))) float;
using bf16x8 = __attribute__((ext_vector_type(8))) short;

constexpr int kB = 4, kC = 256, kL = 2048, kH = 8;

__device__ __forceinline__ unsigned short f2bf(float f) {
    unsigned u = __builtin_bit_cast(unsigned, f);
    u += 0x7fffu + ((u >> 16) & 1u);
    return (unsigned short)(u >> 16);
}

__device__ __forceinline__ f32x4 mfma16(bf16x8 a, bf16x8 b, f32x4 c) {
    return __builtin_amdgcn_mfma_f32_16x16x32_bf16(a, b, c, 0, 0, 0);
}

// ---------------------------------------------------------------------------
// fp32 -> bf16 weight conversion
// ---------------------------------------------------------------------------
__global__ __launch_bounds__(256) void cvt_kernel(const float* __restrict__ s,
                                                  unsigned short* __restrict__ d, int n4) {
    int i = blockIdx.x * 256 + threadIdx.x;
    if (i >= n4) return;
    float4 v = ((const float4*)s)[i];
    unsigned lo = (unsigned)f2bf(v.x) | ((unsigned)f2bf(v.y) << 16);
    unsigned hi = (unsigned)f2bf(v.z) | ((unsigned)f2bf(v.w) << 16);
    ((uint2*)d)[i] = make_uint2(lo, hi);
}

// ---------------------------------------------------------------------------
// GroupNorm: one block per (b,group). Outputs hT bf16 [B][L][C].
// Thread t owns n = 8t..8t+7 across all 8 channels of its group.
// ---------------------------------------------------------------------------
__global__ __launch_bounds__(256) void gn_kernel(const float* __restrict__ x,
                                                 const float* __restrict__ gw,
                                                 const float* __restrict__ gb,
                                                 unsigned short* __restrict__ hT) {
    int b = blockIdx.x >> 5, g = blockIdx.x & 31;
    int t = threadIdx.x;
    const float* xp = x + ((size_t)b * kC + g * 8) * kL + 8 * t;

    float v[8][8];
    float s = 0.f, ss = 0.f;
#pragma unroll
    for (int c = 0; c < 8; ++c) {
        float4 a  = *(const float4*)(xp + (size_t)c * kL);
        float4 a2 = *(const float4*)(xp + (size_t)c * kL + 4);
        v[c][0]=a.x; v[c][1]=a.y; v[c][2]=a.z; v[c][3]=a.w;
        v[c][4]=a2.x; v[c][5]=a2.y; v[c][6]=a2.z; v[c][7]=a2.w;
        s  += (a.x+a.y)+(a.z+a.w)+(a2.x+a2.y)+(a2.z+a2.w);
        ss += a.x*a.x+a.y*a.y+a.z*a.z+a.w*a.w+a2.x*a2.x+a2.y*a2.y+a2.z*a2.z+a2.w*a2.w;
    }
#pragma unroll
    for (int off = 32; off; off >>= 1) {
        s  += __shfl_down(s, off);
        ss += __shfl_down(ss, off);
    }
    __shared__ float red[8];
    int wv = t >> 6;
    if ((t & 63) == 0) { red[wv] = s; red[4 + wv] = ss; }
    __syncthreads();
    s  = red[0] + red[1] + red[2] + red[3];
    ss = red[4] + red[5] + red[6] + red[7];
    float mean = s * (1.f / 16384.f);
    float var  = ss * (1.f / 16384.f) - mean * mean;
    float rstd = rsqrtf(var + 1e-5f);

    float wc[8], bc[8];
#pragma unroll
    for (int c = 0; c < 8; ++c) { wc[c] = gw[g*8+c] * rstd; bc[c] = gb[g*8+c]; }

    unsigned short* hp = hT + ((size_t)b * kL + 8 * t) * kC + g * 8;
#pragma unroll
    for (int j = 0; j < 8; ++j) {
        unsigned pk[4];
#pragma unroll
        for (int c2 = 0; c2 < 4; ++c2) {
            unsigned short l0 = f2bf((v[2*c2  ][j] - mean) * wc[2*c2  ] + bc[2*c2  ]);
            unsigned short h0 = f2bf((v[2*c2+1][j] - mean) * wc[2*c2+1] + bc[2*c2+1]);
            pk[c2] = (unsigned)l0 | ((unsigned)h0 << 16);
        }
        *(uint4*)(hp + (size_t)j * kC) = make_uint4(pk[0], pk[1], pk[2], pk[3]);
    }
}

// ---------------------------------------------------------------------------
// QK GEMM (transposed output): D'[n][o] = sum_c hT[n][c] * W[o][c]  (o<512)
// A-frag = hT rows (n, k contiguous), B-frag = W rows (col o, k contiguous).
// Stores qT/kT [B][H][L][32] bf16, q scaled by 1/sqrt(D), bias fused.
// ---------------------------------------------------------------------------
__global__ __launch_bounds__(256) void qk_gemm(const unsigned short* __restrict__ Wb,
                                               const unsigned short* __restrict__ hT,
                                               const float* __restrict__ qkvb,
                                               unsigned short* __restrict__ qT,
                                               unsigned short* __restrict__ kT) {
    int n0 = blockIdx.x * 64, o0 = blockIdx.y * 64, b = blockIdx.z;
    int t = threadIdx.x, wv = t >> 6, ll = t & 15, lg = (t >> 4) & 3;
    const unsigned short* hb = hT + (size_t)b * kL * kC;

    f32x4 acc[4] = {};
    int arow = n0 + wv * 16 + ll;
    for (int k0 = 0; k0 < 256; k0 += 32) {
        bf16x8 a = *(const bf16x8*)(hb + (size_t)arow * 256 + k0 + 8 * lg);
#pragma unroll
        for (int oj = 0; oj < 4; ++oj) {
            bf16x8 wf = *(const bf16x8*)(Wb + (size_t)(o0 + 16*oj + ll) * 256 + k0 + 8 * lg);
            acc[oj] = mfma16(a, wf, acc[oj]);
        }
    }
#pragma unroll
    for (int oj = 0; oj < 4; ++oj) {
        int o = o0 + 16 * oj + ll;
        float bias = qkvb[o];
        unsigned short* base = (o < 256) ? qT : kT;
        int h = (o >> 5) & 7, d = o & 31;
#pragma unroll
        for (int r = 0; r < 4; ++r) {
            int n = n0 + wv * 16 + 4 * lg + r;
            float val = acc[oj][r] + bias;
            if (o < 256) val *= 0.17677669529663687f;
            base[(((size_t)b * kH + h) * kL + n) * 32 + d] = f2bf(val);
        }
    }
}

// ---------------------------------------------------------------------------
// V GEMM (natural output): D[o][n] = sum_c W[512+o][c] * hT[n][c]
// Stores v [B][256][L] bf16, bias fused.
// ---------------------------------------------------------------------------
__global__ __launch_bounds__(256) void v_gemm(const unsigned short* __restrict__ Wb,
                                              const unsigned short* __restrict__ hT,
                                              const float* __restrict__ qkvb,
                                              unsigned short* __restrict__ vbuf) {
    int n0 = blockIdx.x * 64, o0 = blockIdx.y * 64, b = blockIdx.z;
    int t = threadIdx.x, wv = t >> 6, ll = t & 15, lg = (t >> 4) & 3;
    const unsigned short* hb = hT + (size_t)b * kL * kC;

    f32x4 acc[4] = {};
    int arow = 512 + o0 + wv * 16 + ll;
    for (int k0 = 0; k0 < 256; k0 += 32) {
        bf16x8 a = *(const bf16x8*)(Wb + (size_t)arow * 256 + k0 + 8 * lg);
#pragma unroll
        for (int nj = 0; nj < 4; ++nj) {
            bf16x8 hf = *(const bf16x8*)(hb + (size_t)(n0 + 16*nj + ll) * 256 + k0 + 8 * lg);
            acc[nj] = mfma16(a, hf, acc[nj]);
        }
    }
#pragma unroll
    for (int nj = 0; nj < 4; ++nj) {
#pragma unroll
        for (int r = 0; r < 4; ++r) {
            int o = o0 + wv * 16 + 4 * lg + r;
            int n = n0 + 16 * nj + ll;
            float val = acc[nj][r] + qkvb[512 + o];
            vbuf[((size_t)b * kC + o) * kL + n] = f2bf(val);
        }
    }
}

// ---------------------------------------------------------------------------
// Flash attention, MFMA. Block = 4 waves, wave = 32 queries, 512 blocks.
// S^T = mfma(K-frag, Q-frag) so softmax stats are lane-local per column n.
// P transposed through per-wave padded LDS (no barriers needed).
// PV: D2^T[d][n] = mfma(V-frag, P-frag). Output h2T [B][L][C] bf16.
// ---------------------------------------------------------------------------
__global__ __launch_bounds__(256) void attn_kernel(const unsigned short* __restrict__ qT,
                                                   const unsigned short* __restrict__ kT,
                                                   const unsigned short* __restrict__ vbuf,
                                                   unsigned short* __restrict__ h2T) {
    __shared__ unsigned int Plds[4][32][20];  // [wave][n][m/2 dwords + pad]
    int t = threadIdx.x, wv = t >> 6, ll = t & 15, lg = (t >> 4) & 3;
    int bid = blockIdx.x;
    int qt = bid & 15, bh = bid >> 4;
    int b = bh >> 3, h = bh & 7;
    const unsigned short* qb = qT + (size_t)bh * kL * 32;
    const unsigned short* kb = kT + (size_t)bh * kL * 32;
    const unsigned short* vb = vbuf + ((size_t)b * kC + h * 32) * kL;
    int nbase = qt * 128 + wv * 32;

    bf16x8 qf[2];
#pragma unroll
    for (int nj = 0; nj < 2; ++nj)
        qf[nj] = *(const bf16x8*)(qb + (size_t)(nbase + 16*nj + ll) * 32 + 8 * lg);

    f32x4 acc[2][2] = {};                    // [nj][dj], cols n, rows d
    float mrun[2] = {-1e30f, -1e30f}, lrun[2] = {0.f, 0.f};
    const f32x4 zero = {0.f, 0.f, 0.f, 0.f};

    for (int m0 = 0; m0 < kL; m0 += 32) {
        bf16x8 ka[2];
#pragma unroll
        for (int mj = 0; mj < 2; ++mj)
            ka[mj] = *(const bf16x8*)(kb + (size_t)(m0 + 16*mj + ll) * 32 + 8 * lg);

        f32x4 s[2][2];
#pragma unroll
        for (int mj = 0; mj < 2; ++mj)
#pragma unroll
            for (int nj = 0; nj < 2; ++nj)
                s[mj][nj] = mfma16(ka[mj], qf[nj], zero);

#pragma unroll
        for (int nj = 0; nj < 2; ++nj) {
            float tm = s[0][nj][0];
#pragma unroll
            for (int r = 1; r < 4; ++r) tm = fmaxf(tm, s[0][nj][r]);
#pragma unroll
            for (int r = 0; r < 4; ++r) tm = fmaxf(tm, s[1][nj][r]);
            tm = fmaxf(tm, __shfl_xor(tm, 16));
            tm = fmaxf(tm, __shfl_xor(tm, 32));
            float mnew = fmaxf(mrun[nj], tm);
            float corr = __expf(mrun[nj] - mnew);
            mrun[nj] = mnew;

            float ts = 0.f;
            unsigned pw[2][2];
#pragma unroll
            for (int mj = 0; mj < 2; ++mj) {
                float p0 = __expf(s[mj][nj][0] - mnew);
                float p1 = __expf(s[mj][nj][1] - mnew);
                float p2 = __expf(s[mj][nj][2] - mnew);
                float p3 = __expf(s[mj][nj][3] - mnew);
                ts += (p0 + p1) + (p2 + p3);
                pw[mj][0] = (unsigned)f2bf(p0) | ((unsigned)f2bf(p1) << 16);
                pw[mj][1] = (unsigned)f2bf(p2) | ((unsigned)f2bf(p3) << 16);
            }
            ts += __shfl_xor(ts, 16);
            ts += __shfl_xor(ts, 32);
            lrun[nj] = lrun[nj] * corr + ts;
#pragma unroll
            for (int dj = 0; dj < 2; ++dj)
#pragma unroll
                for (int r = 0; r < 4; ++r) acc[nj][dj][r] *= corr;

#pragma unroll
            for (int mj = 0; mj < 2; ++mj)
                *(uint2*)&Plds[wv][ll + 16*nj][8*mj + 2*lg] = make_uint2(pw[mj][0], pw[mj][1]);
        }

        bf16x8 pbf[2];
#pragma unroll
        for (int nj = 0; nj < 2; ++nj)
            pbf[nj] = *(bf16x8*)&Plds[wv][ll + 16*nj][4 * lg];

#pragma unroll
        for (int dj = 0; dj < 2; ++dj) {
            bf16x8 va = *(const bf16x8*)(vb + (size_t)(16*dj + ll) * kL + m0 + 8 * lg);
#pragma unroll
            for (int nj = 0; nj < 2; ++nj)
                acc[nj][dj] = mfma16(va, pbf[nj], acc[nj][dj]);
        }
    }

    unsigned short* ob = h2T + (size_t)b * kL * kC + h * 32;
#pragma unroll
    for (int nj = 0; nj < 2; ++nj) {
        float inv = 1.f / lrun[nj];
        int n = nbase + 16 * nj + ll;
#pragma unroll
        for (int dj = 0; dj < 2; ++dj)
#pragma unroll
            for (int r = 0; r < 4; ++r) {
                int d = 16 * dj + 4 * lg + r;
                ob[(size_t)n * kC + d] = f2bf(acc[nj][dj][r] * inv);
            }
    }
}

// ---------------------------------------------------------------------------
// OUT GEMM (natural): out[o][n] = sum_c Wout[o][c]*h2T[n][c] + bias + x, fp32.
// ---------------------------------------------------------------------------
__global__ __launch_bounds__(256) void out_gemm(const unsigned short* __restrict__ Wb,
                                                const unsigned short* __restrict__ h2T,
                                                const float* __restrict__ outb,
                                                const float* __restrict__ x,
                                                float* __restrict__ out) {
    int n0 = blockIdx.x * 64, o0 = blockIdx.y * 64, b = blockIdx.z;
    int t = threadIdx.x, wv = t >> 6, ll = t & 15, lg = (t >> 4) & 3;
    const unsigned short* hb = h2T + (size_t)b * kL * kC;

    f32x4 acc[4] = {};
    int arow = o0 + wv * 16 + ll;
    for (int k0 = 0; k0 < 256; k0 += 32) {
        bf16x8 a = *(const bf16x8*)(Wb + (size_t)arow * 256 + k0 + 8 * lg);
#pragma unroll
        for (int nj = 0; nj < 4; ++nj) {
            bf16x8 hf = *(const bf16x8*)(hb + (size_t)(n0 + 16*nj + ll) * 256 + k0 + 8 * lg);
            acc[nj] = mfma16(a, hf, acc[nj]);
        }
    }
#pragma unroll
    for (int nj = 0; nj < 4; ++nj) {
#pragma unroll
        for (int r = 0; r < 4; ++r) {
            int o = o0 + wv * 16 + 4 * lg + r;
            int n = n0 + 16 * nj + ll;
            float val = acc[nj][r] + outb[o] + x[((size_t)b * kC + o) * kL + n];
            out[((size_t)b * kC + o) * kL + n] = val;
        }
    }
}

// ---------------------------------------------------------------------------
extern "C" void kernel_launch(void* const* d_in, const int* in_sizes, int n_in,
                              void* d_out, int out_size, void* d_ws, size_t ws_size,
                              hipStream_t stream) {
    const float* x     = (const float*)d_in[0];
    const float* gn_w  = (const float*)d_in[1];
    const float* gn_b  = (const float*)d_in[2];
    const float* qkv_w = (const float*)d_in[3];
    const float* qkv_b = (const float*)d_in[4];
    const float* out_w = (const float*)d_in[5];
    const float* out_b = (const float*)d_in[6];
    float* out = (float*)d_out;

    char* ws = (char*)d_ws;
    const size_t MB = 1024 * 1024;
    unsigned short* hT   = (unsigned short*)(ws);             // 4 MB
    unsigned short* qT   = (unsigned short*)(ws + 4  * MB);   // 4 MB
    unsigned short* kT   = (unsigned short*)(ws + 8  * MB);   // 4 MB
    unsigned short* vbuf = (unsigned short*)(ws + 12 * MB);   // 4 MB
    unsigned short* h2T  = (unsigned short*)(ws + 16 * MB);   // 4 MB
    unsigned short* wqkv = (unsigned short*)(ws + 20 * MB);   // 384 KB
    unsigned short* wout = (unsigned short*)(ws + 21 * MB);   // 128 KB

    cvt_kernel<<<dim3(192), 256, 0, stream>>>(qkv_w, wqkv, 49152);
    cvt_kernel<<<dim3(64),  256, 0, stream>>>(out_w, wout, 16384);
    gn_kernel<<<dim3(kB * 32), 256, 0, stream>>>(x, gn_w, gn_b, hT);
    qk_gemm<<<dim3(32, 8, kB), 256, 0, stream>>>(wqkv, hT, qkv_b, qT, kT);
    v_gemm<<<dim3(32, 4, kB), 256, 0, stream>>>(wqkv, hT, qkv_b, vbuf);
    attn_kernel<<<dim3(512), 256, 0, stream>>>(qT, kT, vbuf, h2T);
    out_gemm<<<dim3(32, 4, kB), 256, 0, stream>>>(wout, h2T, out_b, x, out);
}